// Round 17
// baseline (823.969 us; speedup 1.0000x reference)
//
#include <hip/hip_runtime.h>
#include <hip/hip_bf16.h>
#include <cstdint>

#define B_   2
#define S_   2048
#define D_   4096
#define NH_  32
#define NKV_ 8
#define HD_  128
#define BS_  (B_*S_)      // 4096 rows
#define NQK_ 6144

typedef __bf16 bf16_t;
typedef __bf16 bf16x8 __attribute__((ext_vector_type(8)));
typedef __bf16 bf16x4 __attribute__((ext_vector_type(4)));
typedef __bf16 bf16x2 __attribute__((ext_vector_type(2)));
typedef float  f32x4  __attribute__((ext_vector_type(4)));
typedef float  f32x16 __attribute__((ext_vector_type(16)));
typedef unsigned uint32x4 __attribute__((ext_vector_type(4)));

typedef const __attribute__((address_space(1))) void* gas_ptr;
typedef __attribute__((address_space(3))) void* las_ptr;

__device__ __forceinline__ void gload_lds16(const void* g, void* l) {
  __builtin_amdgcn_global_load_lds((gas_ptr)g, (las_ptr)l, 16, 0, 0);
}

__device__ __forceinline__ float exp2_fast(float x) {   // v_exp_f32 = 2^x
  float r;
  asm("v_exp_f32 %0, %1" : "=v"(r) : "v"(x));
  return r;
}

__device__ __forceinline__ unsigned cvt_pk_bf16(float a, float b) {
  unsigned r;
  asm("v_cvt_pk_bf16_f32 %0, %1, %2" : "=v"(r) : "v"(a), "v"(b));
  return r;
}

#define LD8(p) (*(const bf16x8*)(p))
#define MFMA(a, b, c) __builtin_amdgcn_mfma_f32_16x16x32_bf16(a, b, c, 0, 0, 0)
#define MFMA32(a, b, c) __builtin_amdgcn_mfma_f32_32x32x16_bf16(a, b, c, 0, 0, 0)

// ---------------- f32 -> bf16 convert (vectorized) ----------------
__global__ __launch_bounds__(256) void k_cvt(const float4* __restrict__ in,
                                             bf16x4* __restrict__ out, int n4) {
  int i = blockIdx.x * 256 + threadIdx.x;
  if (i >= n4) return;
  float4 v = in[i];
  bf16x4 o = { (bf16_t)v.x, (bf16_t)v.y, (bf16_t)v.z, (bf16_t)v.w };
  out[i] = o;
}

// ---------------- w[K][N] f32 -> wt[N][K] bf16 (tiled transpose) ----------------
__global__ __launch_bounds__(256) void k_transpose_cvt(const float* __restrict__ w,
                                                       bf16_t* __restrict__ wt,
                                                       int K, int N) {
  __shared__ float tile[32][33];
  int n0 = blockIdx.x * 32, k0 = blockIdx.y * 32;
  int tx = threadIdx.x, ty = threadIdx.y;   // 32x8
#pragma unroll
  for (int i = 0; i < 4; i++)
    tile[ty + 8*i][tx] = w[(size_t)(k0 + ty + 8*i) * N + n0 + tx];
  __syncthreads();
#pragma unroll
  for (int i = 0; i < 4; i++)
    wt[(size_t)(n0 + ty + 8*i) * K + k0 + tx] = (bf16_t)tile[tx][ty + 8*i];
}

// ---------------- 256x256 NT GEMM body (4-phase/K-tile, NF=4) ------------------
// Shared by the merged-QKV kernel and the out-proj kernel via a macro-free
// inline: parameters resolved per-block before the K loop.
template <typename CT>
__device__ __forceinline__ void gemm_body(const bf16_t* __restrict__ Ab,
                                          const bf16_t* __restrict__ Bb,
                                          CT* __restrict__ C, int Nst, int K,
                                          int NT, int bm_row0,
                                          bf16_t* As0, bf16_t* As1,
                                          bf16_t* Bs0, bf16_t* Bs1) {
  constexpr int NF = 4;
  bf16_t* AsArr[2] = { As0, As1 };
  bf16_t* BsArr[2] = { Bs0, Bs1 };
  const int tid = threadIdx.x;
  const int l = tid & 63, w = tid >> 6;
  const int lr = l & 15, lg = l >> 4;
  const int wm = w >> 2, wn = w & 3;       // 2M x 4N wave grid

  int st_row[4], st_col[4], st_dst[4];
#pragma unroll
  for (int j = 0; j < 4; j++) {
    int o = (j * 512 + tid) * 16;          // byte offset
    int row = o >> 7, cb = o & 127;        // 128B rows
    st_row[j] = row;
    st_col[j] = (cb ^ ((row & 7) << 4)) >> 1;
    st_dst[j] = o >> 1;
  }

  int aoff[8], boff[NF];
#pragma unroll
  for (int m = 0; m < 8; m++) {
    int r = wm * 128 + m * 16 + lr;
    aoff[m] = r * 64 + (((lg * 16) ^ ((r & 7) << 4)) >> 1);
  }
#pragma unroll
  for (int n = 0; n < NF; n++) {
    int r = wn * 64 + n * 16 + lr;
    boff[n] = r * 64 + (((lg * 16) ^ ((r & 7) << 4)) >> 1);
  }

  f32x4 acc[8][NF];
#pragma unroll
  for (int m = 0; m < 8; m++)
#pragma unroll
    for (int n = 0; n < NF; n++) acc[m][n] = f32x4{0.f, 0.f, 0.f, 0.f};

  auto stageA = [&](int k, int h) {       // half h: 128 rows, 2 loads
    const int kt = k << 6;
    const int rof = h << 7;
#pragma unroll
    for (int j = 0; j < 2; j++)
      gload_lds16(Ab + (size_t)(st_row[j] + rof) * K + kt + st_col[j],
                  AsArr[k & 1] + (rof << 6) + st_dst[j]);
  };
  auto stageB = [&](int k) {              // full B tile: 256 rows, 4 loads
    const int kt = k << 6;
#pragma unroll
    for (int j = 0; j < NF; j++)
      gload_lds16(Bb + (size_t)st_row[j] * K + kt + st_col[j],
                  BsArr[k & 1] + st_dst[j]);
  };

  stageA(0, 0); stageA(0, 1); stageB(0); stageB(1);
  asm volatile("s_waitcnt vmcnt(4)" ::: "memory");
  __builtin_amdgcn_s_barrier();

  for (int k = 0; k < NT; ++k) {
    const bf16_t* Ap = AsArr[k & 1];
    const bf16_t* Bp = BsArr[k & 1];
    const bool s1 = (k + 1 < NT), s2 = (k + 2 < NT);
    bf16x8 bfr[NF], a[4];

    // ---- P0: b kk0 + a[0..3] kk0 ; stage A-half0(k+1) ----
#pragma unroll
    for (int n = 0; n < NF; n++) bfr[n] = LD8(Bp + boff[n]);
#pragma unroll
    for (int m = 0; m < 4; m++) a[m] = LD8(Ap + aoff[m]);
    if (s1) stageA(k + 1, 0);
    __builtin_amdgcn_s_barrier();
    asm volatile("s_waitcnt lgkmcnt(0)" ::: "memory");
    __builtin_amdgcn_s_setprio(1);
#pragma unroll
    for (int m = 0; m < 4; m++)
#pragma unroll
      for (int n = 0; n < NF; n++)
        acc[m][n] = MFMA(a[m], bfr[n], acc[m][n]);
    __builtin_amdgcn_s_setprio(0);
    __builtin_amdgcn_s_barrier();

    // ---- P1: a[4..7] kk0 ; stage A-half1(k+1) ----
#pragma unroll
    for (int m = 0; m < 4; m++) a[m] = LD8(Ap + aoff[m + 4]);
    if (s1) stageA(k + 1, 1);
    __builtin_amdgcn_s_barrier();
    asm volatile("s_waitcnt lgkmcnt(0)" ::: "memory");
    __builtin_amdgcn_s_setprio(1);
#pragma unroll
    for (int m = 0; m < 4; m++)
#pragma unroll
      for (int n = 0; n < NF; n++)
        acc[m + 4][n] = MFMA(a[m], bfr[n], acc[m + 4][n]);
    __builtin_amdgcn_s_setprio(0);
    __builtin_amdgcn_s_barrier();

    // ---- P2: b kk1 + a[0..3] kk1 ----
#pragma unroll
    for (int n = 0; n < NF; n++) bfr[n] = LD8(Bp + (boff[n] ^ 32));
#pragma unroll
    for (int m = 0; m < 4; m++) a[m] = LD8(Ap + (aoff[m] ^ 32));
    __builtin_amdgcn_s_barrier();
    asm volatile("s_waitcnt lgkmcnt(0)" ::: "memory");
    __builtin_amdgcn_s_setprio(1);
#pragma unroll
    for (int m = 0; m < 4; m++)
#pragma unroll
      for (int n = 0; n < NF; n++)
        acc[m][n] = MFMA(a[m], bfr[n], acc[m][n]);
    __builtin_amdgcn_s_setprio(0);
    __builtin_amdgcn_s_barrier();

    // ---- P3: a[4..7] kk1 ; stage B(k+2) ; boundary vmcnt ----
#pragma unroll
    for (int m = 0; m < 4; m++) a[m] = LD8(Ap + (aoff[m + 4] ^ 32));
    if (s2) {
      stageB(k + 2);
      asm volatile("s_waitcnt vmcnt(4)" ::: "memory");
    } else if (s1) {
      asm volatile("s_waitcnt vmcnt(0)" ::: "memory");
    }
    __builtin_amdgcn_s_barrier();
    asm volatile("s_waitcnt lgkmcnt(0)" ::: "memory");
    __builtin_amdgcn_s_setprio(1);
#pragma unroll
    for (int m = 0; m < 4; m++)
#pragma unroll
      for (int n = 0; n < NF; n++)
        acc[m + 4][n] = MFMA(a[m], bfr[n], acc[m + 4][n]);
    __builtin_amdgcn_s_setprio(0);
    __builtin_amdgcn_s_barrier();
  }

#pragma unroll
  for (int m = 0; m < 8; m++) {
    int row0 = bm_row0 + wm * 128 + m * 16 + lg * 4;
#pragma unroll
    for (int n = 0; n < NF; n++) {
      int col = wn * 64 + n * 16 + lr;
#pragma unroll
      for (int i = 0; i < 4; i++)
        C[(size_t)(row0 + i) * Nst + col] = (CT)acc[m][n][i];
    }
  }
}

// ---------------- merged QKV projection: one 512-block launch ------------------
// grid (16, 32): by<16 -> Q-proj (64 K-tiles, C=qc stride D_);
// by in [16,24) -> KV split-K z=0 (32 K-tiles, C=partA stride 2048);
// by in [24,32) -> KV split-K z=1 (kOff=2048, C=partB stride 2048).
__global__ __launch_bounds__(512, 2) void k_gemm_qkv(const bf16_t* __restrict__ A,
                                                     const bf16_t* __restrict__ Wq,
                                                     const bf16_t* __restrict__ Wkv,
                                                     bf16_t* __restrict__ qc,
                                                     bf16_t* __restrict__ pA,
                                                     bf16_t* __restrict__ pB) {
  __shared__ __align__(16) bf16_t As[2][256 * 64];
  __shared__ __align__(16) bf16_t Bs[2][256 * 64];
  const int bm = blockIdx.x, by = blockIdx.y;
  const bf16_t* Bb;
  bf16_t* Cb;
  int Nst, NT, kOff;
  if (by < 16)      { Bb = Wq  + (size_t)by * 256 * D_;        Cb = qc + by * 256;        Nst = D_;   NT = 64; kOff = 0; }
  else if (by < 24) { Bb = Wkv + (size_t)(by - 16) * 256 * D_; Cb = pA + (by - 16) * 256; Nst = 2048; NT = 32; kOff = 0; }
  else              { Bb = Wkv + (size_t)(by - 24) * 256 * D_; Cb = pB + (by - 24) * 256; Nst = 2048; NT = 32; kOff = 2048; }
  gemm_body<bf16_t>(A + (size_t)bm * 256 * D_ + kOff, Bb + kOff, Cb, Nst, D_, NT,
                    bm * 256, &As[0][0], &As[1][0], &Bs[0][0], &Bs[1][0]);
}

// ---------------- out projection (f32 C) ----------------
__global__ __launch_bounds__(512, 2) void k_gemm_out(const bf16_t* __restrict__ A,
                                                     const bf16_t* __restrict__ Bt,
                                                     float* __restrict__ C) {
  __shared__ __align__(16) bf16_t As[2][256 * 64];
  __shared__ __align__(16) bf16_t Bs[2][256 * 64];
  const int bm = blockIdx.x, bn = blockIdx.y;
  gemm_body<float>(A + (size_t)bm * 256 * D_, Bt + (size_t)bn * 256 * D_,
                   C + bn * 256, D_, D_, 64, bm * 256,
                   &As[0][0], &As[1][0], &Bs[0][0], &Bs[1][0]);
}

// ---------------- RoPE + head-major reorder (optionally sums two parts) -------
__global__ __launch_bounds__(256) void k_rope(const bf16_t* __restrict__ s1,
                                              const bf16_t* __restrict__ s2,
                                              const float* __restrict__ fcos,
                                              const float* __restrict__ fsin,
                                              bf16_t* __restrict__ dst,
                                              int nheads, int stride, float mul) {
  int idx = blockIdx.x * 256 + threadIdx.x;
  int p = idx & 63;
  int h = (idx >> 6) % nheads;
  int bs = idx / (64 * nheads);
  int s = bs & (S_ - 1);
  int b = bs >> 11;
  size_t off = (size_t)bs * stride + h * HD_ + 2 * p;
  bf16x2 ab = *(const bf16x2*)(s1 + off);
  float a = (float)ab[0], bb = (float)ab[1];
  if (s2) {
    bf16x2 ab2 = *(const bf16x2*)(s2 + off);
    a += (float)ab2[0]; bb += (float)ab2[1];
  }
  float c = fcos[s * 64 + p], sn = fsin[s * 64 + p];
  bf16x2 o = { (bf16_t)((a * c - bb * sn) * mul), (bf16_t)((a * sn + bb * c) * mul) };
  *(bf16x2*)(dst + ((((size_t)b * nheads + h) * S_ + s) * HD_) + 2 * p) = o;
}

// ---------------- V transpose from KV parts: -> vt[B][NKV][HD][S] -------------
__global__ __launch_bounds__(256) void k_vtrans(const bf16_t* __restrict__ pA,
                                                const bf16_t* __restrict__ pB,
                                                bf16_t* __restrict__ vtr) {
  __shared__ bf16_t tile[32][33];
  int s0 = blockIdx.x * 32, d0 = blockIdx.y * 32, z = blockIdx.z;  // z = b*NKV+kvh
  int b = z >> 3, kvh = z & 7;
  int tx = threadIdx.x, ty = threadIdx.y;
#pragma unroll
  for (int i = 0; i < 4; i++) {
    size_t off = (size_t)(b * S_ + s0 + ty + 8*i) * 2048 + 1024 + kvh * HD_ + d0 + tx;
    tile[ty + 8*i][tx] = (bf16_t)((float)pA[off] + (float)pB[off]);
  }
  __syncthreads();
#pragma unroll
  for (int i = 0; i < 4; i++)
    vtr[((size_t)z * HD_ + d0 + ty + 8*i) * S_ + s0 + tx] = tile[tx][ty + 8*i];
}

// ---------------- Flash attention (round-15 version, verified 164 us) ---------
// 32x32x16 MFMA, swapped QK^T, in-register softmax (log2 domain, per-lane
// scalar stats, defer-max), permlane32_swap P-redistribution, full swz16
// layouts (conflicts 7.9e5), LDS-transpose epilogue.
#define KVBLK 64
#define SM_THR 12.0f
__global__ __launch_bounds__(256, 2) void k_flash(const bf16_t* __restrict__ qr,
                                                  const bf16_t* __restrict__ kr,
                                                  const bf16_t* __restrict__ vt,
                                                  bf16_t* __restrict__ ctx) {
  __shared__ __align__(16) bf16_t Ks[2][KVBLK * HD_];   // 2 x 16 KB [s][d] swz16
  __shared__ __align__(16) bf16_t Vs[2][64 * 128];      // 2 x 16 KB [d>>1][..] swz16
  const int tid = threadIdx.x;
  const int l = tid & 63, w = tid >> 6;
  const int q5 = l & 31, h = l >> 5;
  const int qb = blockIdx.x, hh = blockIdx.y, b = blockIdx.z;
  const int kvh = hh >> 2;   // NREP=4

  const bf16_t* qbase = qr + (((size_t)b * NH_ + hh) * S_ + qb * 128 + w * 32) * HD_;
  const bf16_t* kbase = kr + (((size_t)b * NKV_ + kvh) * S_) * HD_;
  const bf16_t* vbase = vt + (((size_t)b * NKV_ + kvh) * HD_) * S_;

  bf16x8 qf[8];
#pragma unroll
  for (int s = 0; s < 8; s++)
    qf[s] = LD8(qbase + q5 * HD_ + s * 16 + h * 8);

  f32x16 acco[4];
#pragma unroll
  for (int db = 0; db < 4; db++)
#pragma unroll
    for (int r = 0; r < 16; r++) acco[db][r] = 0.f;
  float mR = -1e30f, lR = 0.f;

  auto stage = [&](int bu, int t) {
    const int kb = t * KVBLK;
#pragma unroll
    for (int j = 0; j < 4; j++) {
      int o_ = (tid + 256 * j) * 16;
      int row = o_ >> 8, cb = o_ & 255;
      int scb = cb ^ ((row & 15) << 4);
      gload_lds16(kbase + (size_t)(kb + row) * HD_ + (scb >> 1),
                  &Ks[bu][0] + (o_ >> 1));
    }
#pragma unroll
    for (int j = 0; j < 4; j++) {
      int o_ = (tid + 256 * j) * 16;
      int row = o_ >> 8, cb = o_ & 255;
      int sin_ = cb ^ ((row & 15) << 4);
      int d = 2 * row + (sin_ >> 7);
      int s0 = (sin_ & 127) >> 1;
      gload_lds16(vbase + (size_t)d * S_ + kb + s0,
                  &Vs[bu][0] + (o_ >> 1));
    }
  };

  const int nt = S_ / KVBLK;
  stage(0, 0);
  __syncthreads();
  int buf = 0;

  for (int t = 0; t < nt; t++) {
    if (t + 1 < nt) stage(buf ^ 1, t + 1);
    const bf16_t* Kb = &Ks[buf][0];
    const bf16_t* Vb = &Vs[buf][0];

    f32x16 accs[2];
#pragma unroll
    for (int kb = 0; kb < 2; kb++)
#pragma unroll
      for (int r = 0; r < 16; r++) accs[kb][r] = 0.f;
    __builtin_amdgcn_s_setprio(1);
#pragma unroll
    for (int s = 0; s < 8; s++) {
#pragma unroll
      for (int kb = 0; kb < 2; kb++) {
        int r = kb * 32 + q5;
        int cb = (32 * s + 16 * h) ^ ((r & 15) << 4);
        bf16x8 kf = LD8(Kb + (r << 7) + (cb >> 1));
        accs[kb] = MFMA32(kf, qf[s], accs[kb]);
      }
    }
    __builtin_amdgcn_s_setprio(0);

    float lm = accs[0][0];
#pragma unroll
    for (int kb = 0; kb < 2; kb++)
#pragma unroll
      for (int r = 0; r < 16; r++)
        if (kb | r) lm = fmaxf(lm, accs[kb][r]);
    if (!__all(lm - mR <= SM_THR)) {
      float fm = fmaxf(lm, __shfl_xor(lm, 32));
      float mnew = fmaxf(mR, fm);
      float alpha = exp2_fast(mR - mnew);
      mR = mnew;
      lR *= alpha;
#pragma unroll
      for (int db = 0; db < 4; db++)
#pragma unroll
        for (int r = 0; r < 16; r++) acco[db][r] *= alpha;
    }
    float psum = 0.f;
    bf16x8 pb[4];
#pragma unroll
    for (int s2 = 0; s2 < 4; s2++) {
      const int kb = s2 >> 1, rb = (s2 & 1) * 8;
      float pv[8];
#pragma unroll
      for (int j = 0; j < 8; j++) {
        pv[j] = exp2_fast(accs[kb][rb + j] - mR);
        psum += pv[j];
      }
      unsigned wlo0 = cvt_pk_bf16(pv[0], pv[1]);
      unsigned wlo1 = cvt_pk_bf16(pv[2], pv[3]);
      unsigned whi0 = cvt_pk_bf16(pv[4], pv[5]);
      unsigned whi1 = cvt_pk_bf16(pv[6], pv[7]);
      asm volatile("v_permlane32_swap_b32 %0, %1" : "+v"(wlo0), "+v"(whi0));
      asm volatile("v_permlane32_swap_b32 %0, %1" : "+v"(wlo1), "+v"(whi1));
      uint32x4 wv = { wlo0, wlo1, whi0, whi1 };
      pb[s2] = __builtin_bit_cast(bf16x8, wv);
    }
    psum += __shfl_xor(psum, 32);
    lR += psum;

    __builtin_amdgcn_s_setprio(1);
#pragma unroll
    for (int s2 = 0; s2 < 4; s2++) {
#pragma unroll
      for (int db = 0; db < 4; db++) {
        int rv = db * 32 + q5;
        int row = rv >> 1;
        int cb = (((rv & 1) << 7) | (32 * s2 + 16 * h)) ^ ((row & 15) << 4);
        bf16x8 vf = LD8(Vb + (row << 7) + (cb >> 1));
        acco[db] = MFMA32(vf, pb[s2], acco[db]);
      }
    }
    __builtin_amdgcn_s_setprio(0);
    __syncthreads();
    buf ^= 1;
  }

  float inv = 1.0f / lR;
  bf16_t* tb = &Ks[0][0] + w * (32 * 128);
#pragma unroll
  for (int db = 0; db < 4; db++)
#pragma unroll
    for (int rp = 0; rp < 8; rp++) {
      int r = 2 * rp;
      int d0 = (r & 3) + 8 * (r >> 2) + 4 * h + 32 * db;
      unsigned word = cvt_pk_bf16(acco[db][r] * inv, acco[db][r + 1] * inv);
      int cbyte = (d0 * 2) ^ ((q5 & 15) << 4);
      *(unsigned*)((char*)tb + q5 * 256 + cbyte) = word;
    }
  __syncthreads();
#pragma unroll
  for (int it = 0; it < 8; it++) {
    int gid = it * 256 + tid;
    int wv = gid >> 9, rem = gid & 511;
    int qq = rem >> 4, g = rem & 15;
    int cbyte = (g * 16) ^ ((qq & 15) << 4);
    bf16x8 v = LD8((const bf16_t*)((const char*)(&Ks[0][0] + wv * (32 * 128)) + qq * 256 + cbyte));
    int srow = qb * 128 + wv * 32 + qq;
    *(bf16x8*)(ctx + ((size_t)(b * S_ + srow)) * D_ + hh * HD_ + g * 8) = v;
  }
}

// ---------------- launch ----------------
extern "C" void kernel_launch(void* const* d_in, const int* in_sizes, int n_in,
                              void* d_out, int out_size, void* d_ws, size_t ws_size,
                              hipStream_t stream) {
  const float* x    = (const float*)d_in[0];
  const float* wq   = (const float*)d_in[1];
  const float* wk   = (const float*)d_in[2];
  const float* wv   = (const float*)d_in[3];
  const float* wo   = (const float*)d_in[4];
  const float* fcos = (const float*)d_in[5];
  const float* fsin = (const float*)d_in[6];
  float* out = (float*)d_out;

  // workspace layout (160 MB, aliased) — see round-13 notes
  const size_t MB = 1u << 20;
  char* p = (char*)d_ws;
  bf16_t* xb    = (bf16_t*)p;
  bf16_t* wqkvt = (bf16_t*)(p + 32 * MB);
  bf16_t* wot   = (bf16_t*)(p + 80 * MB);
  bf16_t* qc    = (bf16_t*)(p + 112 * MB);
  bf16_t* partA = (bf16_t*)(p + 144 * MB);
  bf16_t* partB = wot;
  bf16_t* qrope = xb;
  bf16_t* krope = wqkvt;
  bf16_t* vtr   = wqkvt + (size_t)BS_ * NKV_ * HD_;
  bf16_t* ctx   = qc;

  // Q pre-scale: log2(e) / sqrt(HD)  (scores land in log2 domain)
  const float QSCALE = (float)(0.08838834764831845 * 1.4426950408889634);

  dim3 tb(32, 8);
  // 1. x -> bf16
  k_cvt<<<BS_ * D_ / 1024, 256, 0, stream>>>((const float4*)x, (bf16x4*)xb, BS_ * D_ / 4);
  // 2. transpose+convert q/k/v weights (wo later — its slot holds partB)
  k_transpose_cvt<<<dim3(D_ / 32, D_ / 32), tb, 0, stream>>>(wq, wqkvt, D_, D_);
  k_transpose_cvt<<<dim3(32, D_ / 32), tb, 0, stream>>>(wk, wqkvt + (size_t)D_ * D_, D_, NKV_ * HD_);
  k_transpose_cvt<<<dim3(32, D_ / 32), tb, 0, stream>>>(wv, wqkvt + (size_t)(D_ + NKV_ * HD_) * D_, D_, NKV_ * HD_);
  // 3. merged QKV projection: grid 16x32 = 512 blocks (Q 256 + KV split-K 256)
  k_gemm_qkv<<<dim3(BS_ / 256, 32), 512, 0, stream>>>(
      xb, wqkvt, wqkvt + (size_t)D_ * D_, qc, partA, partB);
  // 4. RoPE + reorder; K/V sum the two split-K parts
  k_rope<<<BS_ * NH_ * 64 / 256, 256, 0, stream>>>(qc, (const bf16_t*)nullptr,
      fcos, fsin, qrope, NH_, D_, QSCALE);
  k_rope<<<BS_ * NKV_ * 64 / 256, 256, 0, stream>>>(partA, partB,
      fcos, fsin, krope, NKV_, 2048, 1.0f);
  k_vtrans<<<dim3(S_ / 32, HD_ / 32, B_ * NKV_), tb, 0, stream>>>(partA, partB, vtr);
  // 5. transpose wo (partB now dead)
  k_transpose_cvt<<<dim3(D_ / 32, D_ / 32), tb, 0, stream>>>(wo, wot, D_, D_);
  // 6. flash attention (round-15 version)
  k_flash<<<dim3(S_ / 128, NH_, B_), 256, 0, stream>>>(qrope, krope, vtr, ctx);
  // 7. output projection -> f32 out: 256 blocks = 1 round
  k_gemm_out<<<dim3(BS_ / 256, D_ / 256), 512, 0, stream>>>(ctx, wot, out);
}

// Round 18
// 568.274 us; speedup vs baseline: 1.4499x; 1.4499x over previous
//
#include <hip/hip_runtime.h>
#include <hip/hip_bf16.h>
#include <cstdint>

#define B_   2
#define S_   2048
#define D_   4096
#define NH_  32
#define NKV_ 8
#define HD_  128
#define BS_  (B_*S_)      // 4096 rows
#define NQK_ 6144

typedef __bf16 bf16_t;
typedef __bf16 bf16x8 __attribute__((ext_vector_type(8)));
typedef __bf16 bf16x4 __attribute__((ext_vector_type(4)));
typedef __bf16 bf16x2 __attribute__((ext_vector_type(2)));
typedef float  f32x4  __attribute__((ext_vector_type(4)));
typedef float  f32x16 __attribute__((ext_vector_type(16)));
typedef unsigned uint32x4 __attribute__((ext_vector_type(4)));

typedef const __attribute__((address_space(1))) void* gas_ptr;
typedef __attribute__((address_space(3))) void* las_ptr;

__device__ __forceinline__ void gload_lds16(const void* g, void* l) {
  __builtin_amdgcn_global_load_lds((gas_ptr)g, (las_ptr)l, 16, 0, 0);
}

__device__ __forceinline__ float exp2_fast(float x) {   // v_exp_f32 = 2^x
  float r;
  asm("v_exp_f32 %0, %1" : "=v"(r) : "v"(x));
  return r;
}

__device__ __forceinline__ unsigned cvt_pk_bf16(float a, float b) {
  unsigned r;
  asm("v_cvt_pk_bf16_f32 %0, %1, %2" : "=v"(r) : "v"(a), "v"(b));
  return r;
}

#define LD8(p) (*(const bf16x8*)(p))
#define MFMA(a, b, c) __builtin_amdgcn_mfma_f32_16x16x32_bf16(a, b, c, 0, 0, 0)
#define MFMA32(a, b, c) __builtin_amdgcn_mfma_f32_32x32x16_bf16(a, b, c, 0, 0, 0)

// ---------------- f32 -> bf16 convert (vectorized) ----------------
__global__ __launch_bounds__(256) void k_cvt(const float4* __restrict__ in,
                                             bf16x4* __restrict__ out, int n4) {
  int i = blockIdx.x * 256 + threadIdx.x;
  if (i >= n4) return;
  float4 v = in[i];
  bf16x4 o = { (bf16_t)v.x, (bf16_t)v.y, (bf16_t)v.z, (bf16_t)v.w };
  out[i] = o;
}

// ---------------- w[K][N] f32 -> wt[N][K] bf16 (tiled transpose) ----------------
__global__ __launch_bounds__(256) void k_transpose_cvt(const float* __restrict__ w,
                                                       bf16_t* __restrict__ wt,
                                                       int K, int N) {
  __shared__ float tile[32][33];
  int n0 = blockIdx.x * 32, k0 = blockIdx.y * 32;
  int tx = threadIdx.x, ty = threadIdx.y;   // 32x8
#pragma unroll
  for (int i = 0; i < 4; i++)
    tile[ty + 8*i][tx] = w[(size_t)(k0 + ty + 8*i) * N + n0 + tx];
  __syncthreads();
#pragma unroll
  for (int i = 0; i < 4; i++)
    wt[(size_t)(n0 + ty + 8*i) * K + k0 + tx] = (bf16_t)tile[tx][ty + 8*i];
}

// ---------------- 256x256 NT GEMM — 4-phase/K-tile template (NF=4) ------------
// Split-K via blockIdx.z (kOff = z*KL, C += z*zsC). All shape params are
// compile-time-stable per launch (round-17 lesson: runtime-variant setup
// defeats constant folding, -50% per block).
template <typename CT>
__global__ __launch_bounds__(512, 2) void k_gemm8p(const bf16_t* __restrict__ A,
                                                   const bf16_t* __restrict__ Bt,
                                                   CT* __restrict__ C,
                                                   int M, int N, int K, int KL,
                                                   long long zsC) {
  constexpr int NF = 4;
  __shared__ __align__(16) bf16_t As[2][256 * 64];       // 2 x 32 KB
  __shared__ __align__(16) bf16_t Bs[2][NF * 64 * 64];   // 2 x 32 KB
  const int tid = threadIdx.x;
  const int l = tid & 63, w = tid >> 6;
  const int lr = l & 15, lg = l >> 4;
  const int wm = w >> 2, wn = w & 3;       // 2M x 4N wave grid

  const int bm = blockIdx.x, bn = blockIdx.y;
  const int kOff = blockIdx.z * KL;

  const bf16_t* Ab = A  + (size_t)bm * 256 * K + kOff;
  const bf16_t* Bb = Bt + (size_t)bn * 256 * K + kOff;
  C += (long long)blockIdx.z * zsC;

  int st_row[4], st_col[4], st_dst[4];
#pragma unroll
  for (int j = 0; j < 4; j++) {
    int o = (j * 512 + tid) * 16;          // byte offset
    int row = o >> 7, cb = o & 127;        // 128B rows
    st_row[j] = row;
    st_col[j] = (cb ^ ((row & 7) << 4)) >> 1;
    st_dst[j] = o >> 1;
  }

  int aoff[8], boff[NF];
#pragma unroll
  for (int m = 0; m < 8; m++) {
    int r = wm * 128 + m * 16 + lr;
    aoff[m] = r * 64 + (((lg * 16) ^ ((r & 7) << 4)) >> 1);
  }
#pragma unroll
  for (int n = 0; n < NF; n++) {
    int r = wn * 64 + n * 16 + lr;
    boff[n] = r * 64 + (((lg * 16) ^ ((r & 7) << 4)) >> 1);
  }

  f32x4 acc[8][NF];
#pragma unroll
  for (int m = 0; m < 8; m++)
#pragma unroll
    for (int n = 0; n < NF; n++) acc[m][n] = f32x4{0.f, 0.f, 0.f, 0.f};

  auto stageA = [&](int k, int h) {       // half h: 128 rows, 2 loads
    const int kt = k << 6;
    const int rof = h << 7;
#pragma unroll
    for (int j = 0; j < 2; j++)
      gload_lds16(Ab + (size_t)(st_row[j] + rof) * K + kt + st_col[j],
                  &As[k & 1][0] + (rof << 6) + st_dst[j]);
  };
  auto stageB = [&](int k) {              // full B tile: 256 rows, 4 loads
    const int kt = k << 6;
#pragma unroll
    for (int j = 0; j < NF; j++)
      gload_lds16(Bb + (size_t)st_row[j] * K + kt + st_col[j],
                  &Bs[k & 1][0] + st_dst[j]);
  };

  const int NT = KL >> 6;
  stageA(0, 0); stageA(0, 1); stageB(0); stageB(1);
  asm volatile("s_waitcnt vmcnt(4)" ::: "memory");
  __builtin_amdgcn_s_barrier();

  for (int k = 0; k < NT; ++k) {
    const bf16_t* Ap = &As[k & 1][0];
    const bf16_t* Bp = &Bs[k & 1][0];
    const bool s1 = (k + 1 < NT), s2 = (k + 2 < NT);
    bf16x8 bfr[NF], a[4];

    // ---- P0: b kk0 + a[0..3] kk0 ; stage A-half0(k+1) ----
#pragma unroll
    for (int n = 0; n < NF; n++) bfr[n] = LD8(Bp + boff[n]);
#pragma unroll
    for (int m = 0; m < 4; m++) a[m] = LD8(Ap + aoff[m]);
    if (s1) stageA(k + 1, 0);
    __builtin_amdgcn_s_barrier();
    asm volatile("s_waitcnt lgkmcnt(0)" ::: "memory");
    __builtin_amdgcn_s_setprio(1);
#pragma unroll
    for (int m = 0; m < 4; m++)
#pragma unroll
      for (int n = 0; n < NF; n++)
        acc[m][n] = MFMA(a[m], bfr[n], acc[m][n]);
    __builtin_amdgcn_s_setprio(0);
    __builtin_amdgcn_s_barrier();

    // ---- P1: a[4..7] kk0 ; stage A-half1(k+1) ----
#pragma unroll
    for (int m = 0; m < 4; m++) a[m] = LD8(Ap + aoff[m + 4]);
    if (s1) stageA(k + 1, 1);
    __builtin_amdgcn_s_barrier();
    asm volatile("s_waitcnt lgkmcnt(0)" ::: "memory");
    __builtin_amdgcn_s_setprio(1);
#pragma unroll
    for (int m = 0; m < 4; m++)
#pragma unroll
      for (int n = 0; n < NF; n++)
        acc[m + 4][n] = MFMA(a[m], bfr[n], acc[m + 4][n]);
    __builtin_amdgcn_s_setprio(0);
    __builtin_amdgcn_s_barrier();

    // ---- P2: b kk1 + a[0..3] kk1 ----
#pragma unroll
    for (int n = 0; n < NF; n++) bfr[n] = LD8(Bp + (boff[n] ^ 32));
#pragma unroll
    for (int m = 0; m < 4; m++) a[m] = LD8(Ap + (aoff[m] ^ 32));
    __builtin_amdgcn_s_barrier();
    asm volatile("s_waitcnt lgkmcnt(0)" ::: "memory");
    __builtin_amdgcn_s_setprio(1);
#pragma unroll
    for (int m = 0; m < 4; m++)
#pragma unroll
      for (int n = 0; n < NF; n++)
        acc[m][n] = MFMA(a[m], bfr[n], acc[m][n]);
    __builtin_amdgcn_s_setprio(0);
    __builtin_amdgcn_s_barrier();

    // ---- P3: a[4..7] kk1 ; stage B(k+2) ; boundary vmcnt ----
#pragma unroll
    for (int m = 0; m < 4; m++) a[m] = LD8(Ap + (aoff[m + 4] ^ 32));
    if (s2) {
      stageB(k + 2);
      asm volatile("s_waitcnt vmcnt(4)" ::: "memory");
    } else if (s1) {
      asm volatile("s_waitcnt vmcnt(0)" ::: "memory");
    }
    __builtin_amdgcn_s_barrier();
    asm volatile("s_waitcnt lgkmcnt(0)" ::: "memory");
    __builtin_amdgcn_s_setprio(1);
#pragma unroll
    for (int m = 0; m < 4; m++)
#pragma unroll
      for (int n = 0; n < NF; n++)
        acc[m + 4][n] = MFMA(a[m], bfr[n], acc[m + 4][n]);
    __builtin_amdgcn_s_setprio(0);
    __builtin_amdgcn_s_barrier();
  }

#pragma unroll
  for (int m = 0; m < 8; m++) {
    int row0 = bm * 256 + wm * 128 + m * 16 + lg * 4;
#pragma unroll
    for (int n = 0; n < NF; n++) {
      int col = bn * 256 + wn * 64 + n * 16 + lr;
#pragma unroll
      for (int i = 0; i < 4; i++)
        C[(size_t)(row0 + i) * N + col] = (CT)acc[m][n][i];
    }
  }
}

// ---------------- RoPE + head-major reorder (optionally sums two parts) -------
__global__ __launch_bounds__(256) void k_rope(const bf16_t* __restrict__ s1,
                                              const bf16_t* __restrict__ s2,
                                              const float* __restrict__ fcos,
                                              const float* __restrict__ fsin,
                                              bf16_t* __restrict__ dst,
                                              int nheads, int stride, float mul) {
  int idx = blockIdx.x * 256 + threadIdx.x;
  int p = idx & 63;
  int h = (idx >> 6) % nheads;
  int bs = idx / (64 * nheads);
  int s = bs & (S_ - 1);
  int b = bs >> 11;
  size_t off = (size_t)bs * stride + h * HD_ + 2 * p;
  bf16x2 ab = *(const bf16x2*)(s1 + off);
  float a = (float)ab[0], bb = (float)ab[1];
  if (s2) {
    bf16x2 ab2 = *(const bf16x2*)(s2 + off);
    a += (float)ab2[0]; bb += (float)ab2[1];
  }
  float c = fcos[s * 64 + p], sn = fsin[s * 64 + p];
  bf16x2 o = { (bf16_t)((a * c - bb * sn) * mul), (bf16_t)((a * sn + bb * c) * mul) };
  *(bf16x2*)(dst + ((((size_t)b * nheads + h) * S_ + s) * HD_) + 2 * p) = o;
}

// ---------------- V transpose from KV parts: -> vt[B][NKV][HD][S] -------------
__global__ __launch_bounds__(256) void k_vtrans(const bf16_t* __restrict__ pA,
                                                const bf16_t* __restrict__ pB,
                                                bf16_t* __restrict__ vtr) {
  __shared__ bf16_t tile[32][33];
  int s0 = blockIdx.x * 32, d0 = blockIdx.y * 32, z = blockIdx.z;  // z = b*NKV+kvh
  int b = z >> 3, kvh = z & 7;
  int tx = threadIdx.x, ty = threadIdx.y;
#pragma unroll
  for (int i = 0; i < 4; i++) {
    size_t off = (size_t)(b * S_ + s0 + ty + 8*i) * 2048 + 1024 + kvh * HD_ + d0 + tx;
    tile[ty + 8*i][tx] = (bf16_t)((float)pA[off] + (float)pB[off]);
  }
  __syncthreads();
#pragma unroll
  for (int i = 0; i < 4; i++)
    vtr[((size_t)z * HD_ + d0 + ty + 8*i) * S_ + s0 + tx] = tile[tx][ty + 8*i];
}

// ---------------- Flash attention: 32x32x16 MFMA, in-register softmax ---------
// (round-15 verified config: 164 us, 92 VGPR, conflicts 7.9e5)
#define KVBLK 64
#define SM_THR 12.0f
__global__ __launch_bounds__(256, 2) void k_flash(const bf16_t* __restrict__ qr,
                                                  const bf16_t* __restrict__ kr,
                                                  const bf16_t* __restrict__ vt,
                                                  bf16_t* __restrict__ ctx) {
  __shared__ __align__(16) bf16_t Ks[2][KVBLK * HD_];   // 2 x 16 KB [s][d] swz16
  __shared__ __align__(16) bf16_t Vs[2][64 * 128];      // 2 x 16 KB [d>>1][..] swz16
  const int tid = threadIdx.x;
  const int l = tid & 63, w = tid >> 6;
  const int q5 = l & 31, h = l >> 5;
  const int qb = blockIdx.x, hh = blockIdx.y, b = blockIdx.z;
  const int kvh = hh >> 2;   // NREP=4

  const bf16_t* qbase = qr + (((size_t)b * NH_ + hh) * S_ + qb * 128 + w * 32) * HD_;
  const bf16_t* kbase = kr + (((size_t)b * NKV_ + kvh) * S_) * HD_;
  const bf16_t* vbase = vt + (((size_t)b * NKV_ + kvh) * HD_) * S_;

  bf16x8 qf[8];
#pragma unroll
  for (int s = 0; s < 8; s++)
    qf[s] = LD8(qbase + q5 * HD_ + s * 16 + h * 8);

  f32x16 acco[4];
#pragma unroll
  for (int db = 0; db < 4; db++)
#pragma unroll
    for (int r = 0; r < 16; r++) acco[db][r] = 0.f;
  float mR = -1e30f, lR = 0.f;

  auto stage = [&](int bu, int t) {
    const int kb = t * KVBLK;
#pragma unroll
    for (int j = 0; j < 4; j++) {
      int o_ = (tid + 256 * j) * 16;
      int row = o_ >> 8, cb = o_ & 255;
      int scb = cb ^ ((row & 15) << 4);
      gload_lds16(kbase + (size_t)(kb + row) * HD_ + (scb >> 1),
                  &Ks[bu][0] + (o_ >> 1));
    }
#pragma unroll
    for (int j = 0; j < 4; j++) {
      int o_ = (tid + 256 * j) * 16;
      int row = o_ >> 8, cb = o_ & 255;
      int sin_ = cb ^ ((row & 15) << 4);
      int d = 2 * row + (sin_ >> 7);
      int s0 = (sin_ & 127) >> 1;
      gload_lds16(vbase + (size_t)d * S_ + kb + s0,
                  &Vs[bu][0] + (o_ >> 1));
    }
  };

  const int nt = S_ / KVBLK;
  stage(0, 0);
  __syncthreads();
  int buf = 0;

  for (int t = 0; t < nt; t++) {
    if (t + 1 < nt) stage(buf ^ 1, t + 1);
    const bf16_t* Kb = &Ks[buf][0];
    const bf16_t* Vb = &Vs[buf][0];

    f32x16 accs[2];
#pragma unroll
    for (int kb = 0; kb < 2; kb++)
#pragma unroll
      for (int r = 0; r < 16; r++) accs[kb][r] = 0.f;
    __builtin_amdgcn_s_setprio(1);
#pragma unroll
    for (int s = 0; s < 8; s++) {
#pragma unroll
      for (int kb = 0; kb < 2; kb++) {
        int r = kb * 32 + q5;
        int cb = (32 * s + 16 * h) ^ ((r & 15) << 4);
        bf16x8 kf = LD8(Kb + (r << 7) + (cb >> 1));
        accs[kb] = MFMA32(kf, qf[s], accs[kb]);
      }
    }
    __builtin_amdgcn_s_setprio(0);

    float lm = accs[0][0];
#pragma unroll
    for (int kb = 0; kb < 2; kb++)
#pragma unroll
      for (int r = 0; r < 16; r++)
        if (kb | r) lm = fmaxf(lm, accs[kb][r]);
    if (!__all(lm - mR <= SM_THR)) {
      float fm = fmaxf(lm, __shfl_xor(lm, 32));
      float mnew = fmaxf(mR, fm);
      float alpha = exp2_fast(mR - mnew);
      mR = mnew;
      lR *= alpha;
#pragma unroll
      for (int db = 0; db < 4; db++)
#pragma unroll
        for (int r = 0; r < 16; r++) acco[db][r] *= alpha;
    }
    float psum = 0.f;
    bf16x8 pb[4];
#pragma unroll
    for (int s2 = 0; s2 < 4; s2++) {
      const int kb = s2 >> 1, rb = (s2 & 1) * 8;
      float pv[8];
#pragma unroll
      for (int j = 0; j < 8; j++) {
        pv[j] = exp2_fast(accs[kb][rb + j] - mR);
        psum += pv[j];
      }
      unsigned wlo0 = cvt_pk_bf16(pv[0], pv[1]);
      unsigned wlo1 = cvt_pk_bf16(pv[2], pv[3]);
      unsigned whi0 = cvt_pk_bf16(pv[4], pv[5]);
      unsigned whi1 = cvt_pk_bf16(pv[6], pv[7]);
      asm volatile("v_permlane32_swap_b32 %0, %1" : "+v"(wlo0), "+v"(whi0));
      asm volatile("v_permlane32_swap_b32 %0, %1" : "+v"(wlo1), "+v"(whi1));
      uint32x4 wv = { wlo0, wlo1, whi0, whi1 };
      pb[s2] = __builtin_bit_cast(bf16x8, wv);
    }
    psum += __shfl_xor(psum, 32);
    lR += psum;

    __builtin_amdgcn_s_setprio(1);
#pragma unroll
    for (int s2 = 0; s2 < 4; s2++) {
#pragma unroll
      for (int db = 0; db < 4; db++) {
        int rv = db * 32 + q5;
        int row = rv >> 1;
        int cb = (((rv & 1) << 7) | (32 * s2 + 16 * h)) ^ ((row & 15) << 4);
        bf16x8 vf = LD8(Vb + (row << 7) + (cb >> 1));
        acco[db] = MFMA32(vf, pb[s2], acco[db]);
      }
    }
    __builtin_amdgcn_s_setprio(0);
    __syncthreads();
    buf ^= 1;
  }

  float inv = 1.0f / lR;
  bf16_t* tb = &Ks[0][0] + w * (32 * 128);
#pragma unroll
  for (int db = 0; db < 4; db++)
#pragma unroll
    for (int rp = 0; rp < 8; rp++) {
      int r = 2 * rp;
      int d0 = (r & 3) + 8 * (r >> 2) + 4 * h + 32 * db;
      unsigned word = cvt_pk_bf16(acco[db][r] * inv, acco[db][r + 1] * inv);
      int cbyte = (d0 * 2) ^ ((q5 & 15) << 4);
      *(unsigned*)((char*)tb + q5 * 256 + cbyte) = word;
    }
  __syncthreads();
#pragma unroll
  for (int it = 0; it < 8; it++) {
    int gid = it * 256 + tid;
    int wv = gid >> 9, rem = gid & 511;
    int qq = rem >> 4, g = rem & 15;
    int cbyte = (g * 16) ^ ((qq & 15) << 4);
    bf16x8 v = LD8((const bf16_t*)((const char*)(&Ks[0][0] + wv * (32 * 128)) + qq * 256 + cbyte));
    int srow = qb * 128 + wv * 32 + qq;
    *(bf16x8*)(ctx + ((size_t)(b * S_ + srow)) * D_ + hh * HD_ + g * 8) = v;
  }
}

// ---------------- launch ----------------
extern "C" void kernel_launch(void* const* d_in, const int* in_sizes, int n_in,
                              void* d_out, int out_size, void* d_ws, size_t ws_size,
                              hipStream_t stream) {
  const float* x    = (const float*)d_in[0];
  const float* wq   = (const float*)d_in[1];
  const float* wk   = (const float*)d_in[2];
  const float* wv   = (const float*)d_in[3];
  const float* wo   = (const float*)d_in[4];
  const float* fcos = (const float*)d_in[5];
  const float* fsin = (const float*)d_in[6];
  float* out = (float*)d_out;

  // workspace layout (160 MB, aliased) — see round-13 notes
  const size_t MB = 1u << 20;
  char* p = (char*)d_ws;
  bf16_t* xb    = (bf16_t*)p;
  bf16_t* wqkvt = (bf16_t*)(p + 32 * MB);
  bf16_t* wot   = (bf16_t*)(p + 80 * MB);
  bf16_t* qc    = (bf16_t*)(p + 112 * MB);
  bf16_t* partA = (bf16_t*)(p + 144 * MB);
  bf16_t* partB = wot;
  bf16_t* qrope = xb;
  bf16_t* krope = wqkvt;
  bf16_t* vtr   = wqkvt + (size_t)BS_ * NKV_ * HD_;
  bf16_t* ctx   = qc;

  // Q pre-scale: log2(e) / sqrt(HD)  (scores land in log2 domain)
  const float QSCALE = (float)(0.08838834764831845 * 1.4426950408889634);

  dim3 tb(32, 8);
  // 1. x -> bf16
  k_cvt<<<BS_ * D_ / 1024, 256, 0, stream>>>((const float4*)x, (bf16x4*)xb, BS_ * D_ / 4);
  // 2. transpose+convert q/k/v weights (wo later — its slot holds partB)
  k_transpose_cvt<<<dim3(D_ / 32, D_ / 32), tb, 0, stream>>>(wq, wqkvt, D_, D_);
  k_transpose_cvt<<<dim3(32, D_ / 32), tb, 0, stream>>>(wk, wqkvt + (size_t)D_ * D_, D_, NKV_ * HD_);
  k_transpose_cvt<<<dim3(32, D_ / 32), tb, 0, stream>>>(wv, wqkvt + (size_t)(D_ + NKV_ * HD_) * D_, D_, NKV_ * HD_);
  // 3a. Q projection: NF=4, 16x16 = 256 blocks = 1 clean round
  k_gemm8p<bf16_t><<<dim3(BS_ / 256, D_ / 256, 1), 512, 0, stream>>>(
      xb, wqkvt, qc, BS_, D_, D_, D_, 0);
  // 3b. KV projection, split-K=2: grid (16,8,2) = 256 blocks = 1 clean round
  k_gemm8p<bf16_t><<<dim3(BS_ / 256, 2048 / 256, 2), 512, 0, stream>>>(
      xb, wqkvt + (size_t)D_ * D_, partA, BS_, 2048, D_, 2048,
      (long long)(partB - partA));
  // 4. RoPE + reorder; K/V sum the two split-K parts
  k_rope<<<BS_ * NH_ * 64 / 256, 256, 0, stream>>>(qc, (const bf16_t*)nullptr,
      fcos, fsin, qrope, NH_, D_, QSCALE);
  k_rope<<<BS_ * NKV_ * 64 / 256, 256, 0, stream>>>(partA, partB,
      fcos, fsin, krope, NKV_, 2048, 1.0f);
  k_vtrans<<<dim3(S_ / 32, HD_ / 32, B_ * NKV_), tb, 0, stream>>>(partA, partB, vtr);
  // 5. transpose wo (partB now dead)
  k_transpose_cvt<<<dim3(D_ / 32, D_ / 32), tb, 0, stream>>>(wo, wot, D_, D_);
  // 6. flash attention (32x32 MFMA, full-width swizzles)
  k_flash<<<dim3(S_ / 128, NH_, B_), 256, 0, stream>>>(qrope, krope, vtr, ctx);
  // 7. output projection -> f32 out: 256 blocks = 1 round
  k_gemm8p<float><<<dim3(BS_ / 256, D_ / 256, 1), 512, 0, stream>>>(
      ctx, wot, out, BS_, D_, D_, D_, 0);
}

// Round 19
// 567.102 us; speedup vs baseline: 1.4529x; 1.0021x over previous
//
#include <hip/hip_runtime.h>
#include <hip/hip_bf16.h>
#include <cstdint>

#define B_   2
#define S_   2048
#define D_   4096
#define NH_  32
#define NKV_ 8
#define HD_  128
#define BS_  (B_*S_)      // 4096 rows
#define NQK_ 6144

typedef __bf16 bf16_t;
typedef __bf16 bf16x8 __attribute__((ext_vector_type(8)));
typedef __bf16 bf16x4 __attribute__((ext_vector_type(4)));
typedef __bf16 bf16x2 __attribute__((ext_vector_type(2)));
typedef float  f32x4  __attribute__((ext_vector_type(4)));
typedef float  f32x16 __attribute__((ext_vector_type(16)));
typedef unsigned uint32x4 __attribute__((ext_vector_type(4)));

typedef const __attribute__((address_space(1))) void* gas_ptr;
typedef __attribute__((address_space(3))) void* las_ptr;

__device__ __forceinline__ void gload_lds16(const void* g, void* l) {
  __builtin_amdgcn_global_load_lds((gas_ptr)g, (las_ptr)l, 16, 0, 0);
}

__device__ __forceinline__ float exp2_fast(float x) {   // v_exp_f32 = 2^x
  float r;
  asm("v_exp_f32 %0, %1" : "=v"(r) : "v"(x));
  return r;
}

__device__ __forceinline__ unsigned cvt_pk_bf16(float a, float b) {
  unsigned r;
  asm("v_cvt_pk_bf16_f32 %0, %1, %2" : "=v"(r) : "v"(a), "v"(b));
  return r;
}

#define LD8(p) (*(const bf16x8*)(p))
#define MFMA(a, b, c) __builtin_amdgcn_mfma_f32_16x16x32_bf16(a, b, c, 0, 0, 0)
#define MFMA32(a, b, c) __builtin_amdgcn_mfma_f32_32x32x16_bf16(a, b, c, 0, 0, 0)

// ---------------- f32 -> bf16 convert (vectorized) ----------------
__global__ __launch_bounds__(256) void k_cvt(const float4* __restrict__ in,
                                             bf16x4* __restrict__ out, int n4) {
  int i = blockIdx.x * 256 + threadIdx.x;
  if (i >= n4) return;
  float4 v = in[i];
  bf16x4 o = { (bf16_t)v.x, (bf16_t)v.y, (bf16_t)v.z, (bf16_t)v.w };
  out[i] = o;
}

// ---------------- w[K][N] f32 -> wt[N][K] bf16 (tiled transpose) ----------------
__global__ __launch_bounds__(256) void k_transpose_cvt(const float* __restrict__ w,
                                                       bf16_t* __restrict__ wt,
                                                       int K, int N) {
  __shared__ float tile[32][33];
  int n0 = blockIdx.x * 32, k0 = blockIdx.y * 32;
  int tx = threadIdx.x, ty = threadIdx.y;   // 32x8
#pragma unroll
  for (int i = 0; i < 4; i++)
    tile[ty + 8*i][tx] = w[(size_t)(k0 + ty + 8*i) * N + n0 + tx];
  __syncthreads();
#pragma unroll
  for (int i = 0; i < 4; i++)
    wt[(size_t)(n0 + ty + 8*i) * K + k0 + tx] = (bf16_t)tile[tx][ty + 8*i];
}

// ---------------- 256x256 NT GEMM — 4-phase/K-tile, A-prefetch depth 2 --------
// Round-19: A staged TWO tiles ahead into a 3-deep rotation (As[3], 96 KB;
// Bs[2], 64 KB; total 160 KB). Rationale: with depth-1 A staging, the P3
// vmcnt waited on A(k+1) issued only 2-3 phases (~500-750 cy) earlier —
// under HBM latency (~900 cy) -> per-tile stall. Now A(k+2) is issued at
// kP0/P1 and waited on at (k+1)P3 = 6+ phases (~1500 cy) of cover.
// WAR: Abuf[(k+2)%3] last read at tile k-1 (k+2 == k-1 mod 3), complete
// before kP0's leading (= (k-1)P3 trailing) barrier. Bbuf[k&1] rewritten at
// kP3 after its last read (kP2) - unchanged. Boundary: vmcnt(8) = A(k+2)+
// B(k+2) in flight, certifies A(k+1)/B(k+1). Never drains mid-loop (T4).
template <typename CT>
__global__ __launch_bounds__(512, 2) void k_gemm8p(const bf16_t* __restrict__ A,
                                                   const bf16_t* __restrict__ Bt,
                                                   CT* __restrict__ C,
                                                   int M, int N, int K, int KL,
                                                   long long zsC) {
  constexpr int NF = 4;
  __shared__ __align__(16) bf16_t As[3][256 * 64];       // 3 x 32 KB
  __shared__ __align__(16) bf16_t Bs[2][NF * 64 * 64];   // 2 x 32 KB
  const int tid = threadIdx.x;
  const int l = tid & 63, w = tid >> 6;
  const int lr = l & 15, lg = l >> 4;
  const int wm = w >> 2, wn = w & 3;       // 2M x 4N wave grid

  const int bm = blockIdx.x, bn = blockIdx.y;
  const int kOff = blockIdx.z * KL;

  const bf16_t* Ab = A  + (size_t)bm * 256 * K + kOff;
  const bf16_t* Bb = Bt + (size_t)bn * 256 * K + kOff;
  C += (long long)blockIdx.z * zsC;

  int st_row[4], st_col[4], st_dst[4];
#pragma unroll
  for (int j = 0; j < 4; j++) {
    int o = (j * 512 + tid) * 16;          // byte offset
    int row = o >> 7, cb = o & 127;        // 128B rows
    st_row[j] = row;
    st_col[j] = (cb ^ ((row & 7) << 4)) >> 1;
    st_dst[j] = o >> 1;
  }

  int aoff[8], boff[NF];
#pragma unroll
  for (int m = 0; m < 8; m++) {
    int r = wm * 128 + m * 16 + lr;
    aoff[m] = r * 64 + (((lg * 16) ^ ((r & 7) << 4)) >> 1);
  }
#pragma unroll
  for (int n = 0; n < NF; n++) {
    int r = wn * 64 + n * 16 + lr;
    boff[n] = r * 64 + (((lg * 16) ^ ((r & 7) << 4)) >> 1);
  }

  f32x4 acc[8][NF];
#pragma unroll
  for (int m = 0; m < 8; m++)
#pragma unroll
    for (int n = 0; n < NF; n++) acc[m][n] = f32x4{0.f, 0.f, 0.f, 0.f};

  auto stageA = [&](int k, int h, int bu) {   // half h: 128 rows, 2 loads
    const int kt = k << 6;
    const int rof = h << 7;
#pragma unroll
    for (int j = 0; j < 2; j++)
      gload_lds16(Ab + (size_t)(st_row[j] + rof) * K + kt + st_col[j],
                  &As[bu][0] + (rof << 6) + st_dst[j]);
  };
  auto stageB = [&](int k) {                  // full B tile: 256 rows, 4 loads
    const int kt = k << 6;
#pragma unroll
    for (int j = 0; j < NF; j++)
      gload_lds16(Bb + (size_t)st_row[j] * K + kt + st_col[j],
                  &Bs[k & 1][0] + st_dst[j]);
  };

  const int NT = KL >> 6;
  // prologue order matters for vmcnt(8): {A0,B0} first 8, {A1,B1} next 8
  stageA(0, 0, 0); stageA(0, 1, 0); stageB(0);
  stageA(1, 0, 1); stageA(1, 1, 1); stageB(1);
  asm volatile("s_waitcnt vmcnt(8)" ::: "memory");   // A0,B0 landed
  __builtin_amdgcn_s_barrier();

  int ra = 0;                                 // k % 3 (A read buffer)
  for (int k = 0; k < NT; ++k) {
    const bf16_t* Ap = &As[ra][0];
    const bf16_t* Bp = &Bs[k & 1][0];
    const bool s1 = (k + 1 < NT), s2 = (k + 2 < NT);
    const int sa = (ra >= 1) ? ra - 1 : 2;    // (k+2) % 3
    bf16x8 bfr[NF], a[4];

    // ---- P0: b kk0 + a[0..3] kk0 ; stage A-half0(k+2) ----
#pragma unroll
    for (int n = 0; n < NF; n++) bfr[n] = LD8(Bp + boff[n]);
#pragma unroll
    for (int m = 0; m < 4; m++) a[m] = LD8(Ap + aoff[m]);
    if (s2) stageA(k + 2, 0, sa);
    __builtin_amdgcn_s_barrier();
    asm volatile("s_waitcnt lgkmcnt(0)" ::: "memory");
    __builtin_amdgcn_s_setprio(1);
#pragma unroll
    for (int m = 0; m < 4; m++)
#pragma unroll
      for (int n = 0; n < NF; n++)
        acc[m][n] = MFMA(a[m], bfr[n], acc[m][n]);
    __builtin_amdgcn_s_setprio(0);
    __builtin_amdgcn_s_barrier();

    // ---- P1: a[4..7] kk0 ; stage A-half1(k+2) ----
#pragma unroll
    for (int m = 0; m < 4; m++) a[m] = LD8(Ap + aoff[m + 4]);
    if (s2) stageA(k + 2, 1, sa);
    __builtin_amdgcn_s_barrier();
    asm volatile("s_waitcnt lgkmcnt(0)" ::: "memory");
    __builtin_amdgcn_s_setprio(1);
#pragma unroll
    for (int m = 0; m < 4; m++)
#pragma unroll
      for (int n = 0; n < NF; n++)
        acc[m + 4][n] = MFMA(a[m], bfr[n], acc[m + 4][n]);
    __builtin_amdgcn_s_setprio(0);
    __builtin_amdgcn_s_barrier();

    // ---- P2: b kk1 + a[0..3] kk1 ----
#pragma unroll
    for (int n = 0; n < NF; n++) bfr[n] = LD8(Bp + (boff[n] ^ 32));
#pragma unroll
    for (int m = 0; m < 4; m++) a[m] = LD8(Ap + (aoff[m] ^ 32));
    __builtin_amdgcn_s_barrier();
    asm volatile("s_waitcnt lgkmcnt(0)" ::: "memory");
    __builtin_amdgcn_s_setprio(1);
#pragma unroll
    for (int m = 0; m < 4; m++)
#pragma unroll
      for (int n = 0; n < NF; n++)
        acc[m][n] = MFMA(a[m], bfr[n], acc[m][n]);
    __builtin_amdgcn_s_setprio(0);
    __builtin_amdgcn_s_barrier();

    // ---- P3: a[4..7] kk1 ; stage B(k+2) ; boundary vmcnt ----
#pragma unroll
    for (int m = 0; m < 4; m++) a[m] = LD8(Ap + (aoff[m + 4] ^ 32));
    if (s2) {
      stageB(k + 2);
      asm volatile("s_waitcnt vmcnt(8)" ::: "memory");
    } else if (s1) {
      asm volatile("s_waitcnt vmcnt(0)" ::: "memory");
    }
    __builtin_amdgcn_s_barrier();
    asm volatile("s_waitcnt lgkmcnt(0)" ::: "memory");
    __builtin_amdgcn_s_setprio(1);
#pragma unroll
    for (int m = 0; m < 4; m++)
#pragma unroll
      for (int n = 0; n < NF; n++)
        acc[m + 4][n] = MFMA(a[m], bfr[n], acc[m + 4][n]);
    __builtin_amdgcn_s_setprio(0);
    __builtin_amdgcn_s_barrier();

    ra = (ra == 2) ? 0 : ra + 1;
  }

#pragma unroll
  for (int m = 0; m < 8; m++) {
    int row0 = bm * 256 + wm * 128 + m * 16 + lg * 4;
#pragma unroll
    for (int n = 0; n < NF; n++) {
      int col = bn * 256 + wn * 64 + n * 16 + lr;
#pragma unroll
      for (int i = 0; i < 4; i++)
        C[(size_t)(row0 + i) * N + col] = (CT)acc[m][n][i];
    }
  }
}

// ---------------- RoPE + head-major reorder (optionally sums two parts) -------
__global__ __launch_bounds__(256) void k_rope(const bf16_t* __restrict__ s1,
                                              const bf16_t* __restrict__ s2,
                                              const float* __restrict__ fcos,
                                              const float* __restrict__ fsin,
                                              bf16_t* __restrict__ dst,
                                              int nheads, int stride, float mul) {
  int idx = blockIdx.x * 256 + threadIdx.x;
  int p = idx & 63;
  int h = (idx >> 6) % nheads;
  int bs = idx / (64 * nheads);
  int s = bs & (S_ - 1);
  int b = bs >> 11;
  size_t off = (size_t)bs * stride + h * HD_ + 2 * p;
  bf16x2 ab = *(const bf16x2*)(s1 + off);
  float a = (float)ab[0], bb = (float)ab[1];
  if (s2) {
    bf16x2 ab2 = *(const bf16x2*)(s2 + off);
    a += (float)ab2[0]; bb += (float)ab2[1];
  }
  float c = fcos[s * 64 + p], sn = fsin[s * 64 + p];
  bf16x2 o = { (bf16_t)((a * c - bb * sn) * mul), (bf16_t)((a * sn + bb * c) * mul) };
  *(bf16x2*)(dst + ((((size_t)b * nheads + h) * S_ + s) * HD_) + 2 * p) = o;
}

// ---------------- V transpose from KV parts: -> vt[B][NKV][HD][S] -------------
__global__ __launch_bounds__(256) void k_vtrans(const bf16_t* __restrict__ pA,
                                                const bf16_t* __restrict__ pB,
                                                bf16_t* __restrict__ vtr) {
  __shared__ bf16_t tile[32][33];
  int s0 = blockIdx.x * 32, d0 = blockIdx.y * 32, z = blockIdx.z;  // z = b*NKV+kvh
  int b = z >> 3, kvh = z & 7;
  int tx = threadIdx.x, ty = threadIdx.y;
#pragma unroll
  for (int i = 0; i < 4; i++) {
    size_t off = (size_t)(b * S_ + s0 + ty + 8*i) * 2048 + 1024 + kvh * HD_ + d0 + tx;
    tile[ty + 8*i][tx] = (bf16_t)((float)pA[off] + (float)pB[off]);
  }
  __syncthreads();
#pragma unroll
  for (int i = 0; i < 4; i++)
    vtr[((size_t)z * HD_ + d0 + ty + 8*i) * S_ + s0 + tx] = tile[tx][ty + 8*i];
}

// ---------------- Flash attention: 32x32x16 MFMA, in-register softmax ---------
// (round-15 verified config: 164 us, 92 VGPR, conflicts 7.9e5 — at its
//  LDS-read floor for this geometry; untouched)
#define KVBLK 64
#define SM_THR 12.0f
__global__ __launch_bounds__(256, 2) void k_flash(const bf16_t* __restrict__ qr,
                                                  const bf16_t* __restrict__ kr,
                                                  const bf16_t* __restrict__ vt,
                                                  bf16_t* __restrict__ ctx) {
  __shared__ __align__(16) bf16_t Ks[2][KVBLK * HD_];   // 2 x 16 KB [s][d] swz16
  __shared__ __align__(16) bf16_t Vs[2][64 * 128];      // 2 x 16 KB [d>>1][..] swz16
  const int tid = threadIdx.x;
  const int l = tid & 63, w = tid >> 6;
  const int q5 = l & 31, h = l >> 5;
  const int qb = blockIdx.x, hh = blockIdx.y, b = blockIdx.z;
  const int kvh = hh >> 2;   // NREP=4

  const bf16_t* qbase = qr + (((size_t)b * NH_ + hh) * S_ + qb * 128 + w * 32) * HD_;
  const bf16_t* kbase = kr + (((size_t)b * NKV_ + kvh) * S_) * HD_;
  const bf16_t* vbase = vt + (((size_t)b * NKV_ + kvh) * HD_) * S_;

  bf16x8 qf[8];
#pragma unroll
  for (int s = 0; s < 8; s++)
    qf[s] = LD8(qbase + q5 * HD_ + s * 16 + h * 8);

  f32x16 acco[4];
#pragma unroll
  for (int db = 0; db < 4; db++)
#pragma unroll
    for (int r = 0; r < 16; r++) acco[db][r] = 0.f;
  float mR = -1e30f, lR = 0.f;

  auto stage = [&](int bu, int t) {
    const int kb = t * KVBLK;
#pragma unroll
    for (int j = 0; j < 4; j++) {
      int o_ = (tid + 256 * j) * 16;
      int row = o_ >> 8, cb = o_ & 255;
      int scb = cb ^ ((row & 15) << 4);
      gload_lds16(kbase + (size_t)(kb + row) * HD_ + (scb >> 1),
                  &Ks[bu][0] + (o_ >> 1));
    }
#pragma unroll
    for (int j = 0; j < 4; j++) {
      int o_ = (tid + 256 * j) * 16;
      int row = o_ >> 8, cb = o_ & 255;
      int sin_ = cb ^ ((row & 15) << 4);
      int d = 2 * row + (sin_ >> 7);
      int s0 = (sin_ & 127) >> 1;
      gload_lds16(vbase + (size_t)d * S_ + kb + s0,
                  &Vs[bu][0] + (o_ >> 1));
    }
  };

  const int nt = S_ / KVBLK;
  stage(0, 0);
  __syncthreads();
  int buf = 0;

  for (int t = 0; t < nt; t++) {
    if (t + 1 < nt) stage(buf ^ 1, t + 1);
    const bf16_t* Kb = &Ks[buf][0];
    const bf16_t* Vb = &Vs[buf][0];

    f32x16 accs[2];
#pragma unroll
    for (int kb = 0; kb < 2; kb++)
#pragma unroll
      for (int r = 0; r < 16; r++) accs[kb][r] = 0.f;
    __builtin_amdgcn_s_setprio(1);
#pragma unroll
    for (int s = 0; s < 8; s++) {
#pragma unroll
      for (int kb = 0; kb < 2; kb++) {
        int r = kb * 32 + q5;
        int cb = (32 * s + 16 * h) ^ ((r & 15) << 4);
        bf16x8 kf = LD8(Kb + (r << 7) + (cb >> 1));
        accs[kb] = MFMA32(kf, qf[s], accs[kb]);
      }
    }
    __builtin_amdgcn_s_setprio(0);

    float lm = accs[0][0];
#pragma unroll
    for (int kb = 0; kb < 2; kb++)
#pragma unroll
      for (int r = 0; r < 16; r++)
        if (kb | r) lm = fmaxf(lm, accs[kb][r]);
    if (!__all(lm - mR <= SM_THR)) {
      float fm = fmaxf(lm, __shfl_xor(lm, 32));
      float mnew = fmaxf(mR, fm);
      float alpha = exp2_fast(mR - mnew);
      mR = mnew;
      lR *= alpha;
#pragma unroll
      for (int db = 0; db < 4; db++)
#pragma unroll
        for (int r = 0; r < 16; r++) acco[db][r] *= alpha;
    }
    float psum = 0.f;
    bf16x8 pb[4];
#pragma unroll
    for (int s2 = 0; s2 < 4; s2++) {
      const int kb = s2 >> 1, rb = (s2 & 1) * 8;
      float pv[8];
#pragma unroll
      for (int j = 0; j < 8; j++) {
        pv[j] = exp2_fast(accs[kb][rb + j] - mR);
        psum += pv[j];
      }
      unsigned wlo0 = cvt_pk_bf16(pv[0], pv[1]);
      unsigned wlo1 = cvt_pk_bf16(pv[2], pv[3]);
      unsigned whi0 = cvt_pk_bf16(pv[4], pv[5]);
      unsigned whi1 = cvt_pk_bf16(pv[6], pv[7]);
      asm volatile("v_permlane32_swap_b32 %0, %1" : "+v"(wlo0), "+v"(whi0));
      asm volatile("v_permlane32_swap_b32 %0, %1" : "+v"(wlo1), "+v"(whi1));
      uint32x4 wv = { wlo0, wlo1, whi0, whi1 };
      pb[s2] = __builtin_bit_cast(bf16x8, wv);
    }
    psum += __shfl_xor(psum, 32);
    lR += psum;

    __builtin_amdgcn_s_setprio(1);
#pragma unroll
    for (int s2 = 0; s2 < 4; s2++) {
#pragma unroll
      for (int db = 0; db < 4; db++) {
        int rv = db * 32 + q5;
        int row = rv >> 1;
        int cb = (((rv & 1) << 7) | (32 * s2 + 16 * h)) ^ ((row & 15) << 4);
        bf16x8 vf = LD8(Vb + (row << 7) + (cb >> 1));
        acco[db] = MFMA32(vf, pb[s2], acco[db]);
      }
    }
    __builtin_amdgcn_s_setprio(0);
    __syncthreads();
    buf ^= 1;
  }

  float inv = 1.0f / lR;
  bf16_t* tb = &Ks[0][0] + w * (32 * 128);
#pragma unroll
  for (int db = 0; db < 4; db++)
#pragma unroll
    for (int rp = 0; rp < 8; rp++) {
      int r = 2 * rp;
      int d0 = (r & 3) + 8 * (r >> 2) + 4 * h + 32 * db;
      unsigned word = cvt_pk_bf16(acco[db][r] * inv, acco[db][r + 1] * inv);
      int cbyte = (d0 * 2) ^ ((q5 & 15) << 4);
      *(unsigned*)((char*)tb + q5 * 256 + cbyte) = word;
    }
  __syncthreads();
#pragma unroll
  for (int it = 0; it < 8; it++) {
    int gid = it * 256 + tid;
    int wv = gid >> 9, rem = gid & 511;
    int qq = rem >> 4, g = rem & 15;
    int cbyte = (g * 16) ^ ((qq & 15) << 4);
    bf16x8 v = LD8((const bf16_t*)((const char*)(&Ks[0][0] + wv * (32 * 128)) + qq * 256 + cbyte));
    int srow = qb * 128 + wv * 32 + qq;
    *(bf16x8*)(ctx + ((size_t)(b * S_ + srow)) * D_ + hh * HD_ + g * 8) = v;
  }
}

// ---------------- launch ----------------
extern "C" void kernel_launch(void* const* d_in, const int* in_sizes, int n_in,
                              void* d_out, int out_size, void* d_ws, size_t ws_size,
                              hipStream_t stream) {
  const float* x    = (const float*)d_in[0];
  const float* wq   = (const float*)d_in[1];
  const float* wk   = (const float*)d_in[2];
  const float* wv   = (const float*)d_in[3];
  const float* wo   = (const float*)d_in[4];
  const float* fcos = (const float*)d_in[5];
  const float* fsin = (const float*)d_in[6];
  float* out = (float*)d_out;

  // workspace layout (160 MB, aliased) — see round-13 notes
  const size_t MB = 1u << 20;
  char* p = (char*)d_ws;
  bf16_t* xb    = (bf16_t*)p;
  bf16_t* wqkvt = (bf16_t*)(p + 32 * MB);
  bf16_t* wot   = (bf16_t*)(p + 80 * MB);
  bf16_t* qc    = (bf16_t*)(p + 112 * MB);
  bf16_t* partA = (bf16_t*)(p + 144 * MB);
  bf16_t* partB = wot;
  bf16_t* qrope = xb;
  bf16_t* krope = wqkvt;
  bf16_t* vtr   = wqkvt + (size_t)BS_ * NKV_ * HD_;
  bf16_t* ctx   = qc;

  // Q pre-scale: log2(e) / sqrt(HD)  (scores land in log2 domain)
  const float QSCALE = (float)(0.08838834764831845 * 1.4426950408889634);

  dim3 tb(32, 8);
  // 1. x -> bf16
  k_cvt<<<BS_ * D_ / 1024, 256, 0, stream>>>((const float4*)x, (bf16x4*)xb, BS_ * D_ / 4);
  // 2. transpose+convert q/k/v weights (wo later — its slot holds partB)
  k_transpose_cvt<<<dim3(D_ / 32, D_ / 32), tb, 0, stream>>>(wq, wqkvt, D_, D_);
  k_transpose_cvt<<<dim3(32, D_ / 32), tb, 0, stream>>>(wk, wqkvt + (size_t)D_ * D_, D_, NKV_ * HD_);
  k_transpose_cvt<<<dim3(32, D_ / 32), tb, 0, stream>>>(wv, wqkvt + (size_t)(D_ + NKV_ * HD_) * D_, D_, NKV_ * HD_);
  // 3a. Q projection: NF=4, 16x16 = 256 blocks = 1 clean round
  k_gemm8p<bf16_t><<<dim3(BS_ / 256, D_ / 256, 1), 512, 0, stream>>>(
      xb, wqkvt, qc, BS_, D_, D_, D_, 0);
  // 3b. KV projection, split-K=2: grid (16,8,2) = 256 blocks = 1 clean round
  k_gemm8p<bf16_t><<<dim3(BS_ / 256, 2048 / 256, 2), 512, 0, stream>>>(
      xb, wqkvt + (size_t)D_ * D_, partA, BS_, 2048, D_, 2048,
      (long long)(partB - partA));
  // 4. RoPE + reorder; K/V sum the two split-K parts
  k_rope<<<BS_ * NH_ * 64 / 256, 256, 0, stream>>>(qc, (const bf16_t*)nullptr,
      fcos, fsin, qrope, NH_, D_, QSCALE);
  k_rope<<<BS_ * NKV_ * 64 / 256, 256, 0, stream>>>(partA, partB,
      fcos, fsin, krope, NKV_, 2048, 1.0f);
  k_vtrans<<<dim3(S_ / 32, HD_ / 32, B_ * NKV_), tb, 0, stream>>>(partA, partB, vtr);
  // 5. transpose wo (partB now dead)
  k_transpose_cvt<<<dim3(D_ / 32, D_ / 32), tb, 0, stream>>>(wo, wot, D_, D_);
  // 6. flash attention (round-15 version, untouched)
  k_flash<<<dim3(S_ / 128, NH_, B_), 256, 0, stream>>>(qrope, krope, vtr, ctx);
  // 7. output projection -> f32 out: 256 blocks = 1 round
  k_gemm8p<float><<<dim3(BS_ / 256, D_ / 256, 1), 512, 0, stream>>>(
      ctx, wot, out, BS_, D_, D_, D_, 0);
}